// Round 1
// 598.089 us; speedup vs baseline: 1.0813x; 1.0813x over previous
//
#include <hip/hip_runtime.h>

typedef unsigned short ushort_t;
typedef __attribute__((ext_vector_type(8))) short bf16x8;
typedef __attribute__((ext_vector_type(4))) float f32x4;

__device__ __forceinline__ ushort_t f2bf(float f) {
    union { float f; unsigned u; } v; v.f = f;
    unsigned r = v.u + 0x7FFFu + ((v.u >> 16) & 1u);
    return (ushort_t)(r >> 16);
}
__device__ __forceinline__ float siluf(float x) { return x / (1.f + __expf(-x)); }
__device__ __forceinline__ float sigm(float x)  { return 1.f / (1.f + __expf(-x)); }

__device__ __forceinline__ void gl2lds16(const void* g, void* l) {
    __builtin_amdgcn_global_load_lds(
        (__attribute__((address_space(1))) void*)(const_cast<void*>(g)),
        (__attribute__((address_space(3))) void*)(l), 16, 0, 0);
}

// Tiled-swizzled bf16 layout ("TS"): [mtile][kslab 0..15][row 0..127][32 k]
// with 16B-chunk swizzle: chunk' = chunk ^ (row&3). Each kslab is 8KB
// contiguous -> global_load_lds streams 1KB/instr; swizzle makes the
// MFMA-fragment ds_read_b128 2-way-conflict (free) instead of 8-way.
__device__ __forceinline__ size_t ts_idx(int mt, int j, int k) {
    return (size_t)mt * 65536 + (size_t)((k >> 5) * 4096) + j * 32
         + ((((k >> 3) & 3) ^ (j & 3)) * 8) + (k & 7);
}

// ---------------- fused weight transpose + PE-constant precompute ----------------
__global__ void k_pt(const float* W_epe, const float* W_ev1, const float* W_ev2,
                     const float* t_pe, const float* W_vpe, const float* b_vpe,
                     const float* b_epe,
                     ushort_t* WT_epe, ushort_t* WT_c, ushort_t* WT_ev2,
                     float* c_v, float* c_e) {
    int n = blockIdx.x, mat = blockIdx.y, t = threadIdx.x;
    if (mat == 3) {
        if (n < 4) {
            int b = n;
            for (int col = t; col < 512; col += 256) {
                float acc = b_epe[col];
                for (int u = 0; u < 100; ++u) acc += t_pe[b*100+u] * W_epe[(512+u)*512 + col];
                c_e[b*512 + col] = acc;
            }
            {
                float acc = b_vpe[t];
                for (int u = 0; u < 100; ++u) acc += t_pe[b*100+u] * W_vpe[(456+u)*256 + t];
                c_v[b*256 + t] = acc;
            }
        }
        return;
    }
    const float* src; ushort_t* dst;
    if (mat == 0)      { src = W_epe;            dst = WT_epe; }
    else if (mat == 1) { src = W_ev1 + 512*512;  dst = WT_c;   }
    else               { src = W_ev2;            dst = WT_ev2; }
    int nt_ = n >> 7, r = n & 127;
    for (int k = t; k < 512; k += 256)
        dst[ts_idx(nt_, r, k)] = f2bf(src[k*512 + n]);
}

// ---------------- fp32 -> TS bf16 conversion of e_f (once) ----------------
__global__ __launch_bounds__(256) void k_cvt(const float* ef, ushort_t* dst) {
    int idx = blockIdx.x * 256 + threadIdx.x;   // 65536 rows * 64 chunks
    int m = idx >> 6, k0 = (idx & 63) * 8;
    const float4* s = (const float4*)(ef + (size_t)m * 512 + k0);
    float4 a = s[0], b = s[1];
    ushort_t* d = dst + ts_idx(m >> 7, m & 127, k0);
    *(ushort4*)d       = make_ushort4(f2bf(a.x), f2bf(a.y), f2bf(a.z), f2bf(a.w));
    *(ushort4*)(d + 4) = make_ushort4(f2bf(b.x), f2bf(b.y), f2bf(b.z), f2bf(b.w));
}

// ---------------- node feature kernels ----------------
__global__ void k_node_v(const float* v_f, const float* p_pe, const float* W_vpe,
                         const float* c_v, float* v) {
    __shared__ float rv[4][256];
    __shared__ float rp[4][200];
    int r0 = blockIdx.x * 4, t = threadIdx.x;
    for (int rr = 0; rr < 4; ++rr) {
        rv[rr][t] = v_f[(r0+rr)*256 + t];
        if (t < 200) rp[rr][t] = p_pe[(r0+rr)*200 + t];
    }
    __syncthreads();
    int b = r0 >> 7;
    float acc[4];
    float cv = c_v[b*256 + t];
    for (int rr = 0; rr < 4; ++rr) acc[rr] = cv;
    for (int k = 0; k < 256; ++k) {
        float w = W_vpe[k*256 + t];
        #pragma unroll
        for (int rr = 0; rr < 4; ++rr) acc[rr] += rv[rr][k] * w;
    }
    for (int k = 0; k < 200; ++k) {
        float w = W_vpe[(256+k)*256 + t];
        #pragma unroll
        for (int rr = 0; rr < 4; ++rr) acc[rr] += rp[rr][k] * w;
    }
    for (int rr = 0; rr < 4; ++rr) v[(r0+rr)*256 + t] = siluf(acc[rr]);
}

__global__ void k_node_proj(const float* v,
                            const float* W_q, const float* b_q,
                            const float* W_k, const float* b_k,
                            const float* W_self, const float* b_self,
                            const float* W_ev1, const float* b_ev1,
                            float* q, float* kk, float* vs, float* P, float* Q) {
    __shared__ float rv[4][256];
    int r0 = blockIdx.x * 4, which = blockIdx.y, t = threadIdx.x;
    for (int rr = 0; rr < 4; ++rr) rv[rr][t] = v[(r0+rr)*256 + t];
    __syncthreads();
    const float* W; const float* bias = nullptr; float* out; bool do_silu = false;
    if (which == 0)      { W = W_q;    bias = b_q;    out = q;  }
    else if (which == 1) { W = W_k;    bias = b_k;    out = kk; }
    else if (which == 2) { W = W_self; bias = b_self; out = vs; do_silu = true; }
    else if (which == 3) { W = W_ev1;  bias = b_ev1;  out = P;  }
    else                 { W = W_ev1 + 256*512;       out = Q;  }
    float acc[4][2] = {};
    for (int k = 0; k < 256; ++k) {
        float w0 = W[k*512 + t];
        float w1 = W[k*512 + t + 256];
        #pragma unroll
        for (int rr = 0; rr < 4; ++rr) {
            acc[rr][0] += rv[rr][k] * w0;
            acc[rr][1] += rv[rr][k] * w1;
        }
    }
    float bb0 = bias ? bias[t] : 0.f;
    float bb1 = bias ? bias[t + 256] : 0.f;
    for (int rr = 0; rr < 4; ++rr) {
        float x0 = acc[rr][0] + bb0;
        float x1 = acc[rr][1] + bb1;
        if (do_silu) { x0 = siluf(x0); x1 = siluf(x1); }
        out[(r0+rr)*512 + t]       = x0;
        out[(r0+rr)*512 + t + 256] = x1;
    }
}

// normalized attention weights: anorm[b,i,j,g] (4*128*128*32 fp32)
__global__ __launch_bounds__(256) void k_attw(const float* q, const float* kmat,
                                              const float* emask, float* anorm) {
    int bi = blockIdx.x; int b = bi >> 7, i = bi & 127;
    int t = threadIdx.x;
    __shared__ __align__(16) float qrow[512];
    __shared__ float s[128][33];
    __shared__ float invd[32];
    qrow[t]       = q[(size_t)bi*512 + t];
    qrow[t + 256] = q[(size_t)bi*512 + t + 256];
    __syncthreads();
    {
        int j = t >> 1, g0 = (t & 1) * 16;
        const float* kr = kmat + ((size_t)b*128 + j) * 512;
        float msk = emask[(size_t)b*16384 + i*128 + j];
        for (int gg = 0; gg < 16; ++gg) {
            int g = g0 + gg;
            const float4* k4 = (const float4*)(kr + g*16);
            const float4* q4 = (const float4*)(qrow + g*16);
            float acc = 0.f;
            #pragma unroll
            for (int c = 0; c < 4; ++c) {
                float4 kv = k4[c], qv = q4[c];
                acc += kv.x*qv.x + kv.y*qv.y + kv.z*qv.z + kv.w*qv.w;
            }
            s[j][g] = sigm(acc * 0.14433756729740645f) * msk;
        }
    }
    __syncthreads();
    if (t < 32) {
        float d = 1e-6f;
        for (int j = 0; j < 128; ++j) d += s[j][t];
        invd[t] = 1.f / d;
    }
    __syncthreads();
    float* dst = anorm + (size_t)bi * 4096;
    for (int idx = t; idx < 4096; idx += 256) {
        int j = idx >> 5, g = idx & 31;
        dst[idx] = s[j][g] * invd[g];
    }
}

// ---------------- unified MFMA GEMM (M=65536, K=512, N=512) ----------------
// 128x128 tile, 4 waves, 16x16x32 bf16 MFMA. A and B both in TS layout
// (tiled 8KB k-slabs, chunk-XOR swizzle). 4-slab LDS ring (16KB/slab = 64KB),
// counted-vmcnt pipeline: 3 slabs in flight, vmcnt(8) steady state (never 0
// in the main loop), one s_barrier per half-step. lgkmcnt(0) before the
// barrier guarantees all waves' ds_reads of the recycled slab are serviced
// before new global_load_lds DMA writes land (WAR safety).
// MODE 0: epi silu(x + c_e[b]) -> TS bf16
// MODE 1: epi silu(x + P[b,i] + Q[b,j]) -> TS bf16
// MODE 2: epi x + b_ev2 -> fp32 row-major out; fused weighted j-reduction -> v2
template <int MODE>
__global__ __launch_bounds__(256) void k_gemm(const ushort_t* A, const ushort_t* BT,
                                              const float* e0, const float* e1,
                                              const float* e2,
                                              ushort_t* out16, float* out32,
                                              float* v2out) {
    __shared__ __align__(16) ushort_t smem[32768];   // 4 slabs x (A 4096 + B 4096)
    int lin = blockIdx.x;
    int xcd = lin & 7, idx = lin >> 3;
    int mt = xcd * 64 + (idx >> 2);
    int nt = idx & 3;
    int n0 = nt * 128;
    int m0 = mt * 128;
    int t = threadIdx.x;
    int wv = t >> 6, lane = t & 63;
    int wm = (wv >> 1) * 64, wn = (wv & 1) * 64;
    int ml = lane & 15, quad = lane >> 4;
    int qs = (quad ^ (ml & 3)) * 8;       // swizzled 16B-chunk offset (ushorts)
    f32x4 acc[4][4] = {};

    const ushort_t* gA = A  + (size_t)mt * 65536 + wv * 512 + lane * 8;
    const ushort_t* gB = BT + (size_t)nt * 65536 + wv * 512 + lane * 8;

    auto issue = [&](int h) {              // stage k-slab h into ring slot h&3
        int slab = h & 3;
        ushort_t* sA = smem + slab * 8192;
        size_t off = (size_t)h * 4096;
        #pragma unroll
        for (int g = 0; g < 2; ++g) {
            gl2lds16(gA + off + g * 2048, sA + (wv + g * 4) * 512);
            gl2lds16(gB + off + g * 2048, sA + 4096 + (wv + g * 4) * 512);
        }
    };
    auto compute = [&](int h) {
        int slab = h & 3;
        const ushort_t* sA = smem + slab * 8192;
        const ushort_t* sB = sA + 4096;
        bf16x8 a[4], b[4];
        #pragma unroll
        for (int tm = 0; tm < 4; ++tm)
            a[tm] = *(const bf16x8*)(sA + (wm + tm * 16 + ml) * 32 + qs);
        #pragma unroll
        for (int tn = 0; tn < 4; ++tn)
            b[tn] = *(const bf16x8*)(sB + (wn + tn * 16 + ml) * 32 + qs);
        #pragma unroll
        for (int tm = 0; tm < 4; ++tm)
            #pragma unroll
            for (int tn = 0; tn < 4; ++tn)
                acc[tm][tn] = __builtin_amdgcn_mfma_f32_16x16x32_bf16(a[tm], b[tn], acc[tm][tn], 0, 0, 0);
    };

    issue(0); issue(1); issue(2);          // 12 loads in flight
    #pragma unroll
    for (int h = 0; h < 16; ++h) {
        // wait for slab h (4 loads) to land; keep up to 8 newer loads in flight.
        if (h < 14)       asm volatile("s_waitcnt vmcnt(8) lgkmcnt(0)" ::: "memory");
        else if (h == 14) asm volatile("s_waitcnt vmcnt(4) lgkmcnt(0)" ::: "memory");
        else              asm volatile("s_waitcnt vmcnt(0) lgkmcnt(0)" ::: "memory");
        __builtin_amdgcn_s_barrier();      // slab h ready everywhere; slot (h+3)&3 free
        if (h < 13) issue(h + 3);
        __builtin_amdgcn_s_setprio(1);
        compute(h);
        __builtin_amdgcn_s_setprio(0);
    }

    int gn0 = n0 + wn + ml;
    if (MODE == 2) {
        __syncthreads();
        float* aw  = (float*)smem;           // 4096 floats (epilogue overlay)
        float* red = aw + 4096;              // 256 floats
        {
            const float4* src = (const float4*)(e1 + (size_t)mt * 4096);
            float4* dw = (float4*)aw;
            for (int i2 = t; i2 < 1024; i2 += 256) dw[i2] = src[i2];
        }
        __syncthreads();
        float bv[4];
        #pragma unroll
        for (int tn = 0; tn < 4; ++tn) bv[tn] = e0[gn0 + tn*16];
        float partial[4] = {0.f, 0.f, 0.f, 0.f};
        #pragma unroll
        for (int tm = 0; tm < 4; ++tm)
            #pragma unroll
            for (int tn = 0; tn < 4; ++tn)
                #pragma unroll
                for (int r = 0; r < 4; ++r) {
                    int j  = wm + tm*16 + quad*4 + r;
                    int gn = gn0 + tn*16;
                    float x = acc[tm][tn][r] + bv[tn];
                    out32[((size_t)m0 + j) * 512 + gn] = x;
                    partial[tn] += aw[j * 32 + (gn >> 4)] * x;
                }
        #pragma unroll
        for (int tn = 0; tn < 4; ++tn) {
            float p = partial[tn];
            p += __shfl_down(p, 32);
            p += __shfl_down(p, 16);
            if (quad == 0 && lane < 16) red[wv * 64 + tn * 16 + ml] = p;
        }
        __syncthreads();
        if (t < 128) {
            int c = t, half = c >> 6, cl = c & 63;
            float tot = red[half * 64 + cl] + red[(half + 2) * 64 + cl];
            size_t o = (size_t)mt * 512 + n0 + c;
            v2out[o] = tot + e2[o];
        }
    } else if (MODE == 1) {
        int brow0 = (mt >> 7) << 7;          // b*128
        float Pv[4];
        #pragma unroll
        for (int tn = 0; tn < 4; ++tn) Pv[tn] = e0[(size_t)mt * 512 + gn0 + tn*16];
        #pragma unroll
        for (int tm = 0; tm < 4; ++tm)
            #pragma unroll
            for (int tn = 0; tn < 4; ++tn)
                #pragma unroll
                for (int r = 0; r < 4; ++r) {
                    int j  = wm + tm*16 + quad*4 + r;
                    int gn = gn0 + tn*16;
                    float x = acc[tm][tn][r] + Pv[tn]
                            + e1[(size_t)(brow0 + j) * 512 + gn];
                    out16[ts_idx(mt, j, gn)] = f2bf(siluf(x));
                }
    } else {
        int b_ = mt >> 7;
        float cv[4];
        #pragma unroll
        for (int tn = 0; tn < 4; ++tn) cv[tn] = e0[b_ * 512 + gn0 + tn*16];
        #pragma unroll
        for (int tm = 0; tm < 4; ++tm)
            #pragma unroll
            for (int tn = 0; tn < 4; ++tn)
                #pragma unroll
                for (int r = 0; r < 4; ++r) {
                    int j  = wm + tm*16 + quad*4 + r;
                    int gn = gn0 + tn*16;
                    float x = acc[tm][tn][r] + cv[tn];
                    out16[ts_idx(mt, j, gn)] = f2bf(siluf(x));
                }
    }
}

// ---------------- fused masked max-pool + output projection ----------------
__global__ __launch_bounds__(256) void k_out(const float* v2, const float* vmask,
                                             const float* W_out, const float* b_out,
                                             float* out) {
    __shared__ float pooled[512];
    __shared__ float rv[4][512];
    __shared__ float vm[128];
    int r0 = blockIdx.x * 4, t = threadIdx.x, b = r0 >> 7;
    if (t < 128) vm[t] = -1e9f * (1.f - vmask[b*128 + t]);
    for (int rr = 0; rr < 4; ++rr) {
        rv[rr][t]       = v2[(size_t)(r0+rr)*512 + t];
        rv[rr][t + 256] = v2[(size_t)(r0+rr)*512 + t + 256];
    }
    __syncthreads();
    for (int d = t; d < 512; d += 256) {
        float m = -1e30f;
        for (int i = 0; i < 128; ++i)
            m = fmaxf(m, v2[((size_t)(b*128 + i))*512 + d] + vm[i]);
        pooled[d] = m;
    }
    __syncthreads();
    float cp = b_out[t];
    for (int d = 0; d < 512; ++d) cp += pooled[d] * W_out[(512 + d)*256 + t];
    float acc[4];
    for (int rr = 0; rr < 4; ++rr) acc[rr] = cp;
    for (int k = 0; k < 512; ++k) {
        float w = W_out[k*256 + t];
        #pragma unroll
        for (int rr = 0; rr < 4; ++rr) acc[rr] += rv[rr][k] * w;
    }
    for (int rr = 0; rr < 4; ++rr) out[(r0+rr)*256 + t] = siluf(acc[rr]);
}

extern "C" void kernel_launch(void* const* d_in, const int* in_sizes, int n_in,
                              void* d_out, int out_size, void* d_ws, size_t ws_size,
                              hipStream_t stream) {
    const float* v_f    = (const float*)d_in[0];
    const float* e_f    = (const float*)d_in[1];
    const float* p_pe   = (const float*)d_in[2];
    const float* t_pe   = (const float*)d_in[3];
    const float* emask  = (const float*)d_in[4];
    const float* vmask  = (const float*)d_in[5];
    const float* W_vpe  = (const float*)d_in[6];
    const float* b_vpe  = (const float*)d_in[7];
    const float* W_epe  = (const float*)d_in[8];
    const float* b_epe  = (const float*)d_in[9];
    const float* W_ev1  = (const float*)d_in[10];
    const float* b_ev1  = (const float*)d_in[11];
    const float* W_ev2  = (const float*)d_in[12];
    const float* b_ev2  = (const float*)d_in[13];
    const float* W_q    = (const float*)d_in[14];
    const float* b_q    = (const float*)d_in[15];
    const float* W_k    = (const float*)d_in[16];
    const float* b_k    = (const float*)d_in[17];
    const float* W_self = (const float*)d_in[18];
    const float* b_self = (const float*)d_in[19];
    const float* W_out  = (const float*)d_in[20];
    const float* b_out  = (const float*)d_in[21];

    float* out_v = (float*)d_out;                 // (4,128,256)
    float* out_e = (float*)d_out + 131072;        // (4,16384,512)

    char* w = (char*)d_ws;
    ushort_t* WT_epe = (ushort_t*)w; w += 512*512*2;
    ushort_t* WT_c   = (ushort_t*)w; w += 512*512*2;
    ushort_t* WT_ev2 = (ushort_t*)w; w += 512*512*2;
    float* c_v   = (float*)w; w += 4*256*4;
    float* c_e   = (float*)w; w += 4*512*4;
    float* v     = (float*)w; w += 512*256*4;
    float* qbuf  = (float*)w; w += 512*512*4;
    float* kbuf  = (float*)w; w += 512*512*4;
    float* vsbuf = (float*)w; w += 512*512*4;
    float* Pbuf  = (float*)w; w += 512*512*4;
    float* Qbuf  = (float*)w; w += 512*512*4;
    float* v2buf = (float*)w; w += 512*512*4;
    float* anorm = (float*)w; w += (size_t)4*128*128*32*4;   // 8 MB
    ushort_t* e16 = (ushort_t*)w; w += (size_t)65536*512*2;  // 67 MB
    ushort_t* h16 = (ushort_t*)w; w += (size_t)65536*512*2;  // 67 MB (also ef16 home)

    k_pt<<<dim3(512, 4), 256, 0, stream>>>(W_epe, W_ev1, W_ev2, t_pe, W_vpe, b_vpe, b_epe,
                                           WT_epe, WT_c, WT_ev2, c_v, c_e);
    // e_f fp32 -> TS bf16, staged in h16 (dead until k_gemm<1> rewrites it)
    k_cvt<<<16384, 256, 0, stream>>>(e_f, h16);
    k_node_v<<<128, 256, 0, stream>>>(v_f, p_pe, W_vpe, c_v, v);
    k_node_proj<<<dim3(128, 5), 256, 0, stream>>>(v, W_q, b_q, W_k, b_k, W_self, b_self,
                                                  W_ev1, b_ev1, qbuf, kbuf, vsbuf, Pbuf, Qbuf);
    k_attw<<<512, 256, 0, stream>>>(qbuf, kbuf, emask, anorm);
    k_gemm<0><<<2048, 256, 0, stream>>>(h16, WT_epe, c_e, nullptr, nullptr, e16, nullptr, nullptr);
    k_gemm<1><<<2048, 256, 0, stream>>>(e16, WT_c, Pbuf, Qbuf, nullptr, h16, nullptr, nullptr);
    k_gemm<2><<<2048, 256, 0, stream>>>(h16, WT_ev2, b_ev2, anorm, vsbuf, nullptr, out_e, v2buf);
    k_out<<<128, 256, 0, stream>>>(v2buf, vmask, W_out, b_out, out_v);
}

// Round 2
// 552.720 us; speedup vs baseline: 1.1701x; 1.0821x over previous
//
#include <hip/hip_runtime.h>

typedef unsigned short ushort_t;
typedef __attribute__((ext_vector_type(8))) short bf16x8;
typedef __attribute__((ext_vector_type(4))) float f32x4;

__device__ __forceinline__ ushort_t f2bf(float f) {
    union { float f; unsigned u; } v; v.f = f;
    unsigned r = v.u + 0x7FFFu + ((v.u >> 16) & 1u);
    return (ushort_t)(r >> 16);
}
__device__ __forceinline__ float siluf(float x) { return x / (1.f + __expf(-x)); }
__device__ __forceinline__ float sigm(float x)  { return 1.f / (1.f + __expf(-x)); }

__device__ __forceinline__ void gl2lds16(const void* g, void* l) {
    __builtin_amdgcn_global_load_lds(
        (__attribute__((address_space(1))) void*)(const_cast<void*>(g)),
        (__attribute__((address_space(3))) void*)(l), 16, 0, 0);
}

// Tiled-swizzled bf16 layout ("TS"): [mtile][kslab 0..15][row 0..127][32 k]
// with 16B-chunk swizzle: chunk' = chunk ^ (row&3). Each kslab is 8KB
// contiguous -> global_load_lds streams 1KB/instr; swizzle makes the
// MFMA-fragment ds_read_b128 2-way-conflict (free) instead of 8-way.
__device__ __forceinline__ size_t ts_idx(int mt, int j, int k) {
    return (size_t)mt * 65536 + (size_t)((k >> 5) * 4096) + j * 32
         + ((((k >> 3) & 3) ^ (j & 3)) * 8) + (k & 7);
}

// ---------------- fused weight transpose + PE-constant precompute ----------------
__global__ void k_pt(const float* W_epe, const float* W_ev1, const float* W_ev2,
                     const float* t_pe, const float* W_vpe, const float* b_vpe,
                     const float* b_epe,
                     ushort_t* WT_epe, ushort_t* WT_c, ushort_t* WT_ev2,
                     float* c_v, float* c_e) {
    int n = blockIdx.x, mat = blockIdx.y, t = threadIdx.x;
    if (mat == 3) {
        if (n < 4) {
            int b = n;
            for (int col = t; col < 512; col += 256) {
                float acc = b_epe[col];
                for (int u = 0; u < 100; ++u) acc += t_pe[b*100+u] * W_epe[(512+u)*512 + col];
                c_e[b*512 + col] = acc;
            }
            {
                float acc = b_vpe[t];
                for (int u = 0; u < 100; ++u) acc += t_pe[b*100+u] * W_vpe[(456+u)*256 + t];
                c_v[b*256 + t] = acc;
            }
        }
        return;
    }
    const float* src; ushort_t* dst;
    if (mat == 0)      { src = W_epe;            dst = WT_epe; }
    else if (mat == 1) { src = W_ev1 + 512*512;  dst = WT_c;   }
    else               { src = W_ev2;            dst = WT_ev2; }
    int nt_ = n >> 7, r = n & 127;
    for (int k = t; k < 512; k += 256)
        dst[ts_idx(nt_, r, k)] = f2bf(src[k*512 + n]);
}

// ---------------- fp32 -> TS bf16 conversion of e_f (once) ----------------
__global__ __launch_bounds__(256) void k_cvt(const float* ef, ushort_t* dst) {
    int idx = blockIdx.x * 256 + threadIdx.x;   // 65536 rows * 64 chunks
    int m = idx >> 6, k0 = (idx & 63) * 8;
    const float4* s = (const float4*)(ef + (size_t)m * 512 + k0);
    float4 a = s[0], b = s[1];
    ushort_t* d = dst + ts_idx(m >> 7, m & 127, k0);
    *(ushort4*)d       = make_ushort4(f2bf(a.x), f2bf(a.y), f2bf(a.z), f2bf(a.w));
    *(ushort4*)(d + 4) = make_ushort4(f2bf(b.x), f2bf(b.y), f2bf(b.z), f2bf(b.w));
}

// ---------------- node feature kernels ----------------
__global__ void k_node_v(const float* v_f, const float* p_pe, const float* W_vpe,
                         const float* c_v, float* v) {
    __shared__ float rv[4][256];
    __shared__ float rp[4][200];
    int r0 = blockIdx.x * 4, t = threadIdx.x;
    for (int rr = 0; rr < 4; ++rr) {
        rv[rr][t] = v_f[(r0+rr)*256 + t];
        if (t < 200) rp[rr][t] = p_pe[(r0+rr)*200 + t];
    }
    __syncthreads();
    int b = r0 >> 7;
    float acc[4];
    float cv = c_v[b*256 + t];
    for (int rr = 0; rr < 4; ++rr) acc[rr] = cv;
    for (int k = 0; k < 256; ++k) {
        float w = W_vpe[k*256 + t];
        #pragma unroll
        for (int rr = 0; rr < 4; ++rr) acc[rr] += rv[rr][k] * w;
    }
    for (int k = 0; k < 200; ++k) {
        float w = W_vpe[(256+k)*256 + t];
        #pragma unroll
        for (int rr = 0; rr < 4; ++rr) acc[rr] += rp[rr][k] * w;
    }
    for (int rr = 0; rr < 4; ++rr) v[(r0+rr)*256 + t] = siluf(acc[rr]);
}

__global__ void k_node_proj(const float* v,
                            const float* W_q, const float* b_q,
                            const float* W_k, const float* b_k,
                            const float* W_self, const float* b_self,
                            const float* W_ev1, const float* b_ev1,
                            float* q, float* kk, float* vs, float* P, float* Q) {
    __shared__ float rv[4][256];
    int r0 = blockIdx.x * 4, which = blockIdx.y, t = threadIdx.x;
    for (int rr = 0; rr < 4; ++rr) rv[rr][t] = v[(r0+rr)*256 + t];
    __syncthreads();
    const float* W; const float* bias = nullptr; float* out; bool do_silu = false;
    if (which == 0)      { W = W_q;    bias = b_q;    out = q;  }
    else if (which == 1) { W = W_k;    bias = b_k;    out = kk; }
    else if (which == 2) { W = W_self; bias = b_self; out = vs; do_silu = true; }
    else if (which == 3) { W = W_ev1;  bias = b_ev1;  out = P;  }
    else                 { W = W_ev1 + 256*512;       out = Q;  }
    float acc[4][2] = {};
    for (int k = 0; k < 256; ++k) {
        float w0 = W[k*512 + t];
        float w1 = W[k*512 + t + 256];
        #pragma unroll
        for (int rr = 0; rr < 4; ++rr) {
            acc[rr][0] += rv[rr][k] * w0;
            acc[rr][1] += rv[rr][k] * w1;
        }
    }
    float bb0 = bias ? bias[t] : 0.f;
    float bb1 = bias ? bias[t + 256] : 0.f;
    for (int rr = 0; rr < 4; ++rr) {
        float x0 = acc[rr][0] + bb0;
        float x1 = acc[rr][1] + bb1;
        if (do_silu) { x0 = siluf(x0); x1 = siluf(x1); }
        out[(r0+rr)*512 + t]       = x0;
        out[(r0+rr)*512 + t + 256] = x1;
    }
}

// normalized attention weights: anorm[b,i,j,g] (4*128*128*32 fp32)
__global__ __launch_bounds__(256) void k_attw(const float* q, const float* kmat,
                                              const float* emask, float* anorm) {
    int bi = blockIdx.x; int b = bi >> 7, i = bi & 127;
    int t = threadIdx.x;
    __shared__ __align__(16) float qrow[512];
    __shared__ float s[128][33];
    __shared__ float invd[32];
    qrow[t]       = q[(size_t)bi*512 + t];
    qrow[t + 256] = q[(size_t)bi*512 + t + 256];
    __syncthreads();
    {
        int j = t >> 1, g0 = (t & 1) * 16;
        const float* kr = kmat + ((size_t)b*128 + j) * 512;
        float msk = emask[(size_t)b*16384 + i*128 + j];
        for (int gg = 0; gg < 16; ++gg) {
            int g = g0 + gg;
            const float4* k4 = (const float4*)(kr + g*16);
            const float4* q4 = (const float4*)(qrow + g*16);
            float acc = 0.f;
            #pragma unroll
            for (int c = 0; c < 4; ++c) {
                float4 kv = k4[c], qv = q4[c];
                acc += kv.x*qv.x + kv.y*qv.y + kv.z*qv.z + kv.w*qv.w;
            }
            s[j][g] = sigm(acc * 0.14433756729740645f) * msk;
        }
    }
    __syncthreads();
    if (t < 32) {
        float d = 1e-6f;
        for (int j = 0; j < 128; ++j) d += s[j][t];
        invd[t] = 1.f / d;
    }
    __syncthreads();
    float* dst = anorm + (size_t)bi * 4096;
    for (int idx = t; idx < 4096; idx += 256) {
        int j = idx >> 5, g = idx & 31;
        dst[idx] = s[j][g] * invd[g];
    }
}

// ---------------- unified MFMA GEMM (M=65536, K=512, N=512) ----------------
// 128x128 tile, 4 waves, 16x16x32 bf16 MFMA. A and B both in TS layout
// (tiled 8KB k-slabs, chunk-XOR swizzle). 4-slab LDS ring (16KB/slab = 64KB),
// counted-vmcnt pipeline: 3 slabs in flight, vmcnt(8) steady state (never 0
// in the main loop), one s_barrier per half-step. lgkmcnt(0) before the
// barrier guarantees all waves' ds_reads of the recycled slab are serviced
// before new global_load_lds DMA writes land (WAR safety).
// MODE 0: epi silu(x + c_e[b]) -> TS bf16
// MODE 1: epi silu(x + P[b,i] + Q[b,j]) -> TS bf16
// MODE 2: epi x + b_ev2 -> fp32 row-major out; fused weighted j-reduction -> v2
template <int MODE>
__global__ __launch_bounds__(256) void k_gemm(const ushort_t* A, const ushort_t* BT,
                                              const float* e0, const float* e1,
                                              const float* e2,
                                              ushort_t* out16, float* out32,
                                              float* v2out) {
    __shared__ __align__(16) ushort_t smem[32768];   // 4 slabs x (A 4096 + B 4096)
    int lin = blockIdx.x;
    int xcd = lin & 7, idx = lin >> 3;
    int mt = xcd * 64 + (idx >> 2);
    int nt = idx & 3;
    int n0 = nt * 128;
    int m0 = mt * 128;
    int t = threadIdx.x;
    int wv = t >> 6, lane = t & 63;
    int wm = (wv >> 1) * 64, wn = (wv & 1) * 64;
    int ml = lane & 15, quad = lane >> 4;
    int qs = (quad ^ (ml & 3)) * 8;       // swizzled 16B-chunk offset (ushorts)
    f32x4 acc[4][4] = {};

    const ushort_t* gA = A  + (size_t)mt * 65536 + wv * 512 + lane * 8;
    const ushort_t* gB = BT + (size_t)nt * 65536 + wv * 512 + lane * 8;

    auto issue = [&](int h) {              // stage k-slab h into ring slot h&3
        int slab = h & 3;
        ushort_t* sA = smem + slab * 8192;
        size_t off = (size_t)h * 4096;
        #pragma unroll
        for (int g = 0; g < 2; ++g) {
            gl2lds16(gA + off + g * 2048, sA + (wv + g * 4) * 512);
            gl2lds16(gB + off + g * 2048, sA + 4096 + (wv + g * 4) * 512);
        }
    };
    auto compute = [&](int h) {
        int slab = h & 3;
        const ushort_t* sA = smem + slab * 8192;
        const ushort_t* sB = sA + 4096;
        bf16x8 a[4], b[4];
        #pragma unroll
        for (int tm = 0; tm < 4; ++tm)
            a[tm] = *(const bf16x8*)(sA + (wm + tm * 16 + ml) * 32 + qs);
        #pragma unroll
        for (int tn = 0; tn < 4; ++tn)
            b[tn] = *(const bf16x8*)(sB + (wn + tn * 16 + ml) * 32 + qs);
        #pragma unroll
        for (int tm = 0; tm < 4; ++tm)
            #pragma unroll
            for (int tn = 0; tn < 4; ++tn)
                acc[tm][tn] = __builtin_amdgcn_mfma_f32_16x16x32_bf16(a[tm], b[tn], acc[tm][tn], 0, 0, 0);
    };

    issue(0); issue(1); issue(2);          // 12 loads in flight
    #pragma unroll
    for (int h = 0; h < 16; ++h) {
        // wait for slab h (4 loads) to land; keep up to 8 newer loads in flight.
        if (h < 14)       asm volatile("s_waitcnt vmcnt(8) lgkmcnt(0)" ::: "memory");
        else if (h == 14) asm volatile("s_waitcnt vmcnt(4) lgkmcnt(0)" ::: "memory");
        else              asm volatile("s_waitcnt vmcnt(0) lgkmcnt(0)" ::: "memory");
        __builtin_amdgcn_s_barrier();      // slab h ready everywhere; slot (h+3)&3 free
        if (h < 13) issue(h + 3);
        __builtin_amdgcn_s_setprio(1);
        compute(h);
        __builtin_amdgcn_s_setprio(0);
    }

    int gn0 = n0 + wn + ml;
    if (MODE == 2) {
        __syncthreads();
        float* aw  = (float*)smem;           // 4096 floats (epilogue overlay)
        float* red = aw + 4096;              // 256 floats
        {
            const float4* src = (const float4*)(e1 + (size_t)mt * 4096);
            float4* dw = (float4*)aw;
            for (int i2 = t; i2 < 1024; i2 += 256) dw[i2] = src[i2];
        }
        __syncthreads();
        float bv[4];
        #pragma unroll
        for (int tn = 0; tn < 4; ++tn) bv[tn] = e0[gn0 + tn*16];
        float partial[4] = {0.f, 0.f, 0.f, 0.f};
        #pragma unroll
        for (int tm = 0; tm < 4; ++tm)
            #pragma unroll
            for (int tn = 0; tn < 4; ++tn)
                #pragma unroll
                for (int r = 0; r < 4; ++r) {
                    int j  = wm + tm*16 + quad*4 + r;
                    int gn = gn0 + tn*16;
                    float x = acc[tm][tn][r] + bv[tn];
                    out32[((size_t)m0 + j) * 512 + gn] = x;
                    partial[tn] += aw[j * 32 + (gn >> 4)] * x;
                }
        #pragma unroll
        for (int tn = 0; tn < 4; ++tn) {
            float p = partial[tn];
            p += __shfl_down(p, 32);
            p += __shfl_down(p, 16);
            if (quad == 0 && lane < 16) red[wv * 64 + tn * 16 + ml] = p;
        }
        __syncthreads();
        if (t < 128) {
            int c = t, half = c >> 6, cl = c & 63;
            float tot = red[half * 64 + cl] + red[(half + 2) * 64 + cl];
            size_t o = (size_t)mt * 512 + n0 + c;
            v2out[o] = tot + e2[o];
        }
    } else if (MODE == 1) {
        int brow0 = (mt >> 7) << 7;          // b*128
        float Pv[4];
        #pragma unroll
        for (int tn = 0; tn < 4; ++tn) Pv[tn] = e0[(size_t)mt * 512 + gn0 + tn*16];
        #pragma unroll
        for (int tm = 0; tm < 4; ++tm)
            #pragma unroll
            for (int tn = 0; tn < 4; ++tn)
                #pragma unroll
                for (int r = 0; r < 4; ++r) {
                    int j  = wm + tm*16 + quad*4 + r;
                    int gn = gn0 + tn*16;
                    float x = acc[tm][tn][r] + Pv[tn]
                            + e1[(size_t)(brow0 + j) * 512 + gn];
                    out16[ts_idx(mt, j, gn)] = f2bf(siluf(x));
                }
    } else {
        int b_ = mt >> 7;
        float cv[4];
        #pragma unroll
        for (int tn = 0; tn < 4; ++tn) cv[tn] = e0[b_ * 512 + gn0 + tn*16];
        #pragma unroll
        for (int tm = 0; tm < 4; ++tm)
            #pragma unroll
            for (int tn = 0; tn < 4; ++tn)
                #pragma unroll
                for (int r = 0; r < 4; ++r) {
                    int j  = wm + tm*16 + quad*4 + r;
                    int gn = gn0 + tn*16;
                    float x = acc[tm][tn][r] + cv[tn];
                    out16[ts_idx(mt, j, gn)] = f2bf(siluf(x));
                }
    }
}

// ---------------- fused masked max-pool + output projection ----------------
// Latency-bound fix (R1): 256 blocks x 1024 threads (16 waves/block, all CUs).
// K=1024 contraction split across 4 k-chunks of 256 (thread = (col, kc));
// pooled-half runs concurrently with the v2-half; LDS combine at the end.
// Pooling parallelized as 512 cols x 2 row-chunks of 64.
__global__ __launch_bounds__(1024) void k_out(const float* v2, const float* vmask,
                                              const float* W_out, const float* b_out,
                                              float* out) {
    __shared__ float rv[2][512];          // this block's 2 rows
    __shared__ float vm[128];
    __shared__ float pm[2][512];
    __shared__ float pooled[512];
    __shared__ float red[2][2][256];      // [kc][row][col]
    __shared__ float cpred[2][256];
    int t = threadIdx.x;
    int r0 = blockIdx.x * 2, b = r0 >> 7;
    if (t < 128) vm[t] = -1e9f * (1.f - vmask[b*128 + t]);
    rv[t >> 9][t & 511] = v2[(size_t)(r0 + (t >> 9)) * 512 + (t & 511)];
    __syncthreads();
    {   // masked max-pool: col = t&511, row-chunk rc = t>>9 (64 rows each)
        int col = t & 511, rc = t >> 9;
        int i0 = rc * 64;
        const float* src = v2 + ((size_t)(b*128 + i0)) * 512 + col;
        float m = -1e30f;
        #pragma unroll 8
        for (int i = 0; i < 64; ++i)
            m = fmaxf(m, src[(size_t)i * 512] + vm[i0 + i]);
        pm[rc][col] = m;
    }
    __syncthreads();
    if (t < 512) pooled[t] = fmaxf(pm[0][t], pm[1][t]);
    __syncthreads();
    {   // projection: col = t&255, k-chunk kc = t>>8
        int col = t & 255, kc = t >> 8;
        if (kc < 2) {
            int k0 = kc * 256;
            float a0 = 0.f, a1 = 0.f;
            #pragma unroll 8
            for (int k = 0; k < 256; ++k) {
                float w = W_out[(size_t)(k0 + k) * 256 + col];
                a0 += rv[0][k0 + k] * w;
                a1 += rv[1][k0 + k] * w;
            }
            red[kc][0][col] = a0;
            red[kc][1][col] = a1;
        } else {
            int d0 = (kc - 2) * 256;
            float cp = 0.f;
            #pragma unroll 8
            for (int d = 0; d < 256; ++d)
                cp += pooled[d0 + d] * W_out[(size_t)(512 + d0 + d) * 256 + col];
            cpred[kc - 2][col] = cp;
        }
    }
    __syncthreads();
    if (t < 512) {
        int row = t >> 8, c = t & 255;
        float x = red[0][row][c] + red[1][row][c]
                + cpred[0][c] + cpred[1][c] + b_out[c];
        out[(size_t)(r0 + row) * 256 + c] = siluf(x);
    }
}

extern "C" void kernel_launch(void* const* d_in, const int* in_sizes, int n_in,
                              void* d_out, int out_size, void* d_ws, size_t ws_size,
                              hipStream_t stream) {
    const float* v_f    = (const float*)d_in[0];
    const float* e_f    = (const float*)d_in[1];
    const float* p_pe   = (const float*)d_in[2];
    const float* t_pe   = (const float*)d_in[3];
    const float* emask  = (const float*)d_in[4];
    const float* vmask  = (const float*)d_in[5];
    const float* W_vpe  = (const float*)d_in[6];
    const float* b_vpe  = (const float*)d_in[7];
    const float* W_epe  = (const float*)d_in[8];
    const float* b_epe  = (const float*)d_in[9];
    const float* W_ev1  = (const float*)d_in[10];
    const float* b_ev1  = (const float*)d_in[11];
    const float* W_ev2  = (const float*)d_in[12];
    const float* b_ev2  = (const float*)d_in[13];
    const float* W_q    = (const float*)d_in[14];
    const float* b_q    = (const float*)d_in[15];
    const float* W_k    = (const float*)d_in[16];
    const float* b_k    = (const float*)d_in[17];
    const float* W_self = (const float*)d_in[18];
    const float* b_self = (const float*)d_in[19];
    const float* W_out  = (const float*)d_in[20];
    const float* b_out  = (const float*)d_in[21];

    float* out_v = (float*)d_out;                 // (4,128,256)
    float* out_e = (float*)d_out + 131072;        // (4,16384,512)

    char* w = (char*)d_ws;
    ushort_t* WT_epe = (ushort_t*)w; w += 512*512*2;
    ushort_t* WT_c   = (ushort_t*)w; w += 512*512*2;
    ushort_t* WT_ev2 = (ushort_t*)w; w += 512*512*2;
    float* c_v   = (float*)w; w += 4*256*4;
    float* c_e   = (float*)w; w += 4*512*4;
    float* v     = (float*)w; w += 512*256*4;
    float* qbuf  = (float*)w; w += 512*512*4;
    float* kbuf  = (float*)w; w += 512*512*4;
    float* vsbuf = (float*)w; w += 512*512*4;
    float* Pbuf  = (float*)w; w += 512*512*4;
    float* Qbuf  = (float*)w; w += 512*512*4;
    float* v2buf = (float*)w; w += 512*512*4;
    float* anorm = (float*)w; w += (size_t)4*128*128*32*4;   // 8 MB
    ushort_t* e16 = (ushort_t*)w; w += (size_t)65536*512*2;  // 67 MB
    ushort_t* h16 = (ushort_t*)w; w += (size_t)65536*512*2;  // 67 MB (also ef16 home)

    k_pt<<<dim3(512, 4), 256, 0, stream>>>(W_epe, W_ev1, W_ev2, t_pe, W_vpe, b_vpe, b_epe,
                                           WT_epe, WT_c, WT_ev2, c_v, c_e);
    // e_f fp32 -> TS bf16, staged in h16 (dead until k_gemm<1> rewrites it)
    k_cvt<<<16384, 256, 0, stream>>>(e_f, h16);
    k_node_v<<<128, 256, 0, stream>>>(v_f, p_pe, W_vpe, c_v, v);
    k_node_proj<<<dim3(128, 5), 256, 0, stream>>>(v, W_q, b_q, W_k, b_k, W_self, b_self,
                                                  W_ev1, b_ev1, qbuf, kbuf, vsbuf, Pbuf, Qbuf);
    k_attw<<<512, 256, 0, stream>>>(qbuf, kbuf, emask, anorm);
    k_gemm<0><<<2048, 256, 0, stream>>>(h16, WT_epe, c_e, nullptr, nullptr, e16, nullptr, nullptr);
    k_gemm<1><<<2048, 256, 0, stream>>>(e16, WT_c, Pbuf, Qbuf, nullptr, h16, nullptr, nullptr);
    k_gemm<2><<<2048, 256, 0, stream>>>(h16, WT_ev2, b_ev2, anorm, vsbuf, nullptr, out_e, v2buf);
    k_out<<<256, 1024, 0, stream>>>(v2buf, vmask, W_out, b_out, out_v);
}